// Round 1
// baseline (652.588 us; speedup 1.0000x reference)
//
#include <hip/hip_runtime.h>

#define N_NODES   10000
#define N_EDGES   640000
#define DIM       128
#define N_GRAPHS  16
#define N_CLASSES 10

constexpr int ROWS = 16;   // rows per block in the dual GEMM

// ---------------------------------------------------------------------------
// K1/K4: out0[r][c] = sum_k A[r][k] * W0[k][c] (+bias0[c])   c = 0..127
//        out1[r][c] = sum_k A[r][k] * W1[k][c] (+bias1[c])   (threads 128..255)
// A is [n_rows, 128] row-major; W0/W1 are [128,128] row-major (row stride 128).
// ---------------------------------------------------------------------------
__global__ __launch_bounds__(256) void gemm_dual(
    const float* __restrict__ A, int n_rows,
    const float* __restrict__ W0, const float* __restrict__ W1,
    const float* __restrict__ bias0, const float* __restrict__ bias1,
    float* __restrict__ out0, int ld0,
    float* __restrict__ out1, int ld1)
{
    __shared__ float xs[ROWS * DIM];
    const int base = blockIdx.x * ROWS;
    const int t    = threadIdx.x;
    const int rows = min(ROWS, n_rows - base);

    for (int i = t; i < rows * DIM; i += 256)
        xs[i] = A[base * DIM + i];
    __syncthreads();

    const int half = t >> 7;        // wave-uniform (waves 0,1 -> 0; waves 2,3 -> 1)
    const int cc   = t & 127;
    const float* __restrict__ W = half ? W1 : W0;

    float acc[ROWS];
#pragma unroll
    for (int r = 0; r < ROWS; ++r) acc[r] = 0.f;

    const float4* xs4 = (const float4*)xs;
    for (int k4 = 0; k4 < DIM / 4; ++k4) {
        const float w0 = W[(k4 * 4 + 0) * DIM + cc];
        const float w1 = W[(k4 * 4 + 1) * DIM + cc];
        const float w2 = W[(k4 * 4 + 2) * DIM + cc];
        const float w3 = W[(k4 * 4 + 3) * DIM + cc];
#pragma unroll
        for (int r = 0; r < ROWS; ++r) {
            const float4 xv = xs4[r * (DIM / 4) + k4];   // LDS broadcast read
            acc[r] = fmaf(xv.x, w0, acc[r]);
            acc[r] = fmaf(xv.y, w1, acc[r]);
            acc[r] = fmaf(xv.z, w2, acc[r]);
            acc[r] = fmaf(xv.w, w3, acc[r]);
        }
    }

    const float* bp = half ? bias1 : bias0;
    const float bv  = bp ? bp[cc] : 0.f;
    float* o        = half ? out1 : out0;
    const int ld    = half ? ld1 : ld0;
    for (int r = 0; r < rows; ++r)
        o[(base + r) * ld + cc] = acc[r] + bv;
}

// ---------------------------------------------------------------------------
// K2: agg[dst[e]][f] += H[src[e]][f]   (one thread per (edge, feature))
// ---------------------------------------------------------------------------
__global__ __launch_bounds__(256) void scatter_add(
    const float* __restrict__ H,
    const int* __restrict__ src, const int* __restrict__ dst,
    float* __restrict__ agg)
{
    const int idx = blockIdx.x * 256 + threadIdx.x;   // < N_EDGES*128
    const int e = idx >> 7;
    const int f = idx & 127;
    if (e < N_EDGES) {
        const int s = src[e];
        const int d = dst[e];
        unsafeAtomicAdd(&agg[d * DIM + f], H[s * DIM + f]);
    }
}

// ---------------------------------------------------------------------------
// K3: z = relu(agg) in place; graph sums + counts via atomics
// ---------------------------------------------------------------------------
__global__ __launch_bounds__(256) void relu_pool(
    float* __restrict__ agg,                 // in: agg+selfterm+b ; out: z_node
    const int* __restrict__ bid,
    float* __restrict__ gsum, float* __restrict__ gcnt)
{
    const int idx = blockIdx.x * 256 + threadIdx.x;   // < N_NODES*128
    const int n = idx >> 7;
    const int f = idx & 127;
    if (n < N_NODES) {
        const float v = fmaxf(agg[idx], 0.f);
        agg[idx] = v;
        const int g = bid[n];
        unsafeAtomicAdd(&gsum[g * DIM + f], v);
        if (f == 0) unsafeAtomicAdd(&gcnt[g], 1.0f);
    }
}

// ---------------------------------------------------------------------------
// K5: wave per edge: p = relu(U1[src] + U2[dst]) . W_e2 + b_e2
// U12 layout: [N, 256]: cols 0..127 = U1 (b_e1 folded in), 128..255 = U2
// ---------------------------------------------------------------------------
__global__ __launch_bounds__(256) void edge_mlp(
    const float* __restrict__ U12,
    const int* __restrict__ src, const int* __restrict__ dst,
    const float* __restrict__ W_e2, const float* __restrict__ b_e2,
    float* __restrict__ out)
{
    const int gid  = blockIdx.x * 256 + threadIdx.x;
    const int e    = gid >> 6;          // wave id == edge id
    const int lane = threadIdx.x & 63;
    if (e >= N_EDGES) return;

    const int s = src[e];
    const int d = dst[e];

    const float2 a  = *(const float2*)&U12[s * 256 + lane * 2];
    const float2 bb = *(const float2*)&U12[d * 256 + 128 + lane * 2];
    const float2 w  = *(const float2*)&W_e2[lane * 2];

    const float v0 = fmaxf(a.x + bb.x, 0.f);
    const float v1 = fmaxf(a.y + bb.y, 0.f);
    float p = v0 * w.x + v1 * w.y;

#pragma unroll
    for (int off = 32; off > 0; off >>= 1)
        p += __shfl_xor(p, off);

    if (lane == 0) out[e] = p + b_e2[0];
}

// ---------------------------------------------------------------------------
// K6: pred_class[g][c] = (gsum[g] . W_cls[:,c]) / max(cnt,1) + b_cls[c]
// ---------------------------------------------------------------------------
__global__ __launch_bounds__(256) void classify(
    const float* __restrict__ gsum, const float* __restrict__ gcnt,
    const float* __restrict__ W_cls, const float* __restrict__ b_cls,
    float* __restrict__ out)
{
    const int t = threadIdx.x;
    if (t >= N_GRAPHS * N_CLASSES) return;
    const int g = t / N_CLASSES;
    const int c = t % N_CLASSES;
    const float inv = 1.0f / fmaxf(gcnt[g], 1.0f);
    float acc = 0.f;
    for (int k = 0; k < DIM; ++k)
        acc += gsum[g * DIM + k] * W_cls[k * N_CLASSES + c];
    out[g * N_CLASSES + c] = acc * inv + b_cls[c];
}

// ---------------------------------------------------------------------------
extern "C" void kernel_launch(void* const* d_in, const int* in_sizes, int n_in,
                              void* d_out, int out_size, void* d_ws, size_t ws_size,
                              hipStream_t stream)
{
    const float* x      = (const float*)d_in[0];
    const int*   eidx   = (const int*)  d_in[1];
    const int*   bid    = (const int*)  d_in[2];
    const float* W_in   = (const float*)d_in[3];
    const float* W_self = (const float*)d_in[4];
    const float* b      = (const float*)d_in[5];
    const float* W_e1   = (const float*)d_in[6];
    const float* b_e1   = (const float*)d_in[7];
    const float* W_e2   = (const float*)d_in[8];
    const float* b_e2   = (const float*)d_in[9];
    const float* W_cls  = (const float*)d_in[10];
    const float* b_cls  = (const float*)d_in[11];
    float* out = (float*)d_out;

    char* ws = (char*)d_ws;
    float* H    = (float*)(ws);                    // [N,128]  5.12 MB
    float* AGG  = (float*)(ws + 5120000);          // [N,128]  5.12 MB (becomes z)
    float* U12  = (float*)(ws + 10240000);         // [N,256] 10.24 MB
    float* gsum = (float*)(ws + 20480000);         // [16,128]
    float* gcnt = (float*)(ws + 20488192);         // [16]

    const int* src = eidx;
    const int* dst = eidx + N_EDGES;

    // zero pooling accumulators (ws is poisoned before every call)
    hipMemsetAsync(gsum, 0, 16 * DIM * 4 + 64, stream);

    // K1: H = x@W_in ; AGG = x@W_self + b
    gemm_dual<<<N_NODES / ROWS, 256, 0, stream>>>(
        x, N_NODES, W_in, W_self, nullptr, b, H, DIM, AGG, DIM);

    // K2: AGG += scatter(H[src] -> dst)
    scatter_add<<<(N_EDGES * DIM) / 256, 256, 0, stream>>>(H, src, dst, AGG);

    // K3: z = relu(AGG); graph sums/counts
    relu_pool<<<(N_NODES * DIM) / 256, 256, 0, stream>>>(AGG, bid, gsum, gcnt);

    // K4: U12 = z @ [W_e1_top | W_e1_bot]  (+b_e1 on U1 half)
    gemm_dual<<<N_NODES / ROWS, 256, 0, stream>>>(
        AGG, N_NODES, W_e1, W_e1 + 128 * DIM, b_e1, nullptr, U12, 256, U12 + 128, 256);

    // K5: per-edge MLP
    edge_mlp<<<(N_EDGES * 64) / 256, 256, 0, stream>>>(U12, src, dst, W_e2, b_e2, out);

    // K6: classifier
    classify<<<1, 256, 0, stream>>>(gsum, gcnt, W_cls, b_cls, out + N_EDGES);
}

// Round 2
// 329.034 us; speedup vs baseline: 1.9833x; 1.9833x over previous
//
#include <hip/hip_runtime.h>

#define N_NODES   10000
#define N_EDGES   640000
#define DIM       128
#define N_GRAPHS  16
#define N_CLASSES 10

typedef unsigned int uint;
typedef unsigned short ushort;

__device__ __forceinline__ float bf2f(uint lo16) {
    return __uint_as_float(lo16 << 16);
}
__device__ __forceinline__ ushort f2bf(float f) {
    uint u = __float_as_uint(f);
    u += 0x7fffu + ((u >> 16) & 1u);      // round-to-nearest-even
    return (ushort)(u >> 16);
}

// ---------------------------------------------------------------------------
// K1: histogram of dst
// ---------------------------------------------------------------------------
__global__ __launch_bounds__(256) void hist_dst(
    const int* __restrict__ dst, int* __restrict__ cnt)
{
    const int e = blockIdx.x * 256 + threadIdx.x;
    if (e < N_EDGES) atomicAdd(&cnt[dst[e]], 1);
}

// ---------------------------------------------------------------------------
// K2: per-graph node counts (batch_ids) -> gcnt (float)
// ---------------------------------------------------------------------------
__global__ __launch_bounds__(256) void count_nodes(
    const int* __restrict__ bid, float* __restrict__ gcnt)
{
    __shared__ int h[N_GRAPHS];
    const int t = threadIdx.x;
    if (t < N_GRAPHS) h[t] = 0;
    __syncthreads();
    for (int n = t; n < N_NODES; n += 256) atomicAdd(&h[bid[n]], 1);
    __syncthreads();
    if (t < N_GRAPHS) gcnt[t] = (float)h[t];
}

// ---------------------------------------------------------------------------
// K3: exclusive prefix sum of cnt[10000] -> cursor (single block)
// ---------------------------------------------------------------------------
__global__ __launch_bounds__(1024) void scan_k(
    const int* __restrict__ cnt, int* __restrict__ cursor)
{
    __shared__ int s[1024];
    const int t = threadIdx.x;
    int local[10];
    int sum = 0;
    if (t < 1000) {
        for (int j = 0; j < 10; ++j) { local[j] = sum; sum += cnt[t * 10 + j]; }
    }
    s[t] = (t < 1000) ? sum : 0;
    __syncthreads();
    for (int st = 1; st < 1024; st <<= 1) {
        int v = (t >= st) ? s[t - st] : 0;
        __syncthreads();
        s[t] += v;
        __syncthreads();
    }
    if (t < 1000) {
        const int off = (t == 0) ? 0 : s[t - 1];
        for (int j = 0; j < 10; ++j) cursor[t * 10 + j] = off + local[j];
    }
}

// ---------------------------------------------------------------------------
// K4: fill CSR: pairs[pos] = (src, edge_id), grouped by dst.
// After this kernel cursor[d] == segment end (start = end - cnt[d]).
// ---------------------------------------------------------------------------
__global__ __launch_bounds__(256) void fill_csr(
    const int* __restrict__ src, const int* __restrict__ dst,
    int* __restrict__ cursor, uint2* __restrict__ pairs)
{
    const int e = blockIdx.x * 256 + threadIdx.x;
    if (e < N_EDGES) {
        const int pos = atomicAdd(&cursor[dst[e]], 1);
        pairs[pos] = make_uint2((uint)src[e], (uint)e);
    }
}

// ---------------------------------------------------------------------------
// K5: XAGG[d] = sum over in-edges of x[src]  (2 nodes per 256-thread block)
// ---------------------------------------------------------------------------
__global__ __launch_bounds__(256) void gather_x(
    const float* __restrict__ x,
    const int* __restrict__ cnt, const int* __restrict__ cursor,
    const uint2* __restrict__ pairs,
    float* __restrict__ XAGG)
{
    const int n = blockIdx.x * 2 + (threadIdx.x >> 7);
    const int c = threadIdx.x & 127;
    const int end = cursor[n];
    const int start = end - cnt[n];
    float acc = 0.f;
    int i = start;
    for (; i + 4 <= end; i += 4) {
        const int s0 = pairs[i].x, s1 = pairs[i + 1].x;
        const int s2 = pairs[i + 2].x, s3 = pairs[i + 3].x;
        acc += x[s0 * DIM + c];
        acc += x[s1 * DIM + c];
        acc += x[s2 * DIM + c];
        acc += x[s3 * DIM + c];
    }
    for (; i < end; ++i) acc += x[pairs[i].x * DIM + c];
    XAGG[n * DIM + c] = acc;
}

// ---------------------------------------------------------------------------
// K6: z = relu(XAGG@W_in + x@W_self + b)  (in place over XAGG)
//     + per-graph sums via run-compressed atomics (batch_ids sorted)
// ---------------------------------------------------------------------------
__global__ __launch_bounds__(256) void gemm_z(
    const float* __restrict__ XAGG_in, const float* __restrict__ x,
    const float* __restrict__ W_in, const float* __restrict__ W_self,
    const float* __restrict__ b, const int* __restrict__ bid,
    float* __restrict__ Z, float* __restrict__ gsum)
{
    __shared__ float sa[16 * DIM];
    __shared__ float sb[16 * DIM];
    __shared__ int sbid[16];
    const int base = blockIdx.x * 16;
    const int t = threadIdx.x;
    {
        const float4* ga = (const float4*)(XAGG_in + base * DIM);
        const float4* gb = (const float4*)(x + base * DIM);
        float4* la = (float4*)sa;
        float4* lb = (float4*)sb;
        for (int i = t; i < 16 * DIM / 4; i += 256) { la[i] = ga[i]; lb[i] = gb[i]; }
        if (t < 16) sbid[t] = bid[base + t];
    }
    __syncthreads();

    const int half = t >> 7, c = t & 127;
    const float* __restrict__ W = half ? W_self : W_in;
    const float4* A4 = (const float4*)(half ? sb : sa);

    float acc[16];
#pragma unroll
    for (int r = 0; r < 16; ++r) acc[r] = 0.f;

    for (int k4 = 0; k4 < DIM / 4; ++k4) {
        const float w0 = W[(k4 * 4 + 0) * DIM + c];
        const float w1 = W[(k4 * 4 + 1) * DIM + c];
        const float w2 = W[(k4 * 4 + 2) * DIM + c];
        const float w3 = W[(k4 * 4 + 3) * DIM + c];
#pragma unroll
        for (int r = 0; r < 16; ++r) {
            const float4 xv = A4[r * (DIM / 4) + k4];
            acc[r] = fmaf(xv.x, w0, acc[r]);
            acc[r] = fmaf(xv.y, w1, acc[r]);
            acc[r] = fmaf(xv.z, w2, acc[r]);
            acc[r] = fmaf(xv.w, w3, acc[r]);
        }
    }
    __syncthreads();
    if (half) {
#pragma unroll
        for (int r = 0; r < 16; ++r) sa[r * DIM + c] = acc[r];
    }
    __syncthreads();
    if (!half) {
        const float bv = b[c];
        float run = 0.f;
        int cur = sbid[0];
#pragma unroll
        for (int r = 0; r < 16; ++r) {
            const float z = fmaxf(acc[r] + sa[r * DIM + c] + bv, 0.f);
            Z[(base + r) * DIM + c] = z;
            const int g = sbid[r];
            if (g != cur) { unsafeAtomicAdd(&gsum[cur * DIM + c], run); run = 0.f; cur = g; }
            run += z;
        }
        unsafeAtomicAdd(&gsum[cur * DIM + c], run);
    }
}

// ---------------------------------------------------------------------------
// K7: U12 = z @ [W_e1_top | W_e1_bot] (+b_e1 on U1 half), bf16 interleaved
// ---------------------------------------------------------------------------
__global__ __launch_bounds__(256) void gemm_u12(
    const float* __restrict__ Z,
    const float* __restrict__ W_e1, const float* __restrict__ b_e1,
    ushort* __restrict__ U12)
{
    __shared__ float xs[16 * DIM];
    const int base = blockIdx.x * 16;
    const int t = threadIdx.x;
    {
        const float4* g = (const float4*)(Z + base * DIM);
        float4* l = (float4*)xs;
        for (int i = t; i < 16 * DIM / 4; i += 256) l[i] = g[i];
    }
    __syncthreads();

    const int half = t >> 7, c = t & 127;
    const float* __restrict__ W = W_e1 + half * 128 * DIM;
    const float4* A4 = (const float4*)xs;

    float acc[16];
#pragma unroll
    for (int r = 0; r < 16; ++r) acc[r] = 0.f;

    for (int k4 = 0; k4 < DIM / 4; ++k4) {
        const float w0 = W[(k4 * 4 + 0) * DIM + c];
        const float w1 = W[(k4 * 4 + 1) * DIM + c];
        const float w2 = W[(k4 * 4 + 2) * DIM + c];
        const float w3 = W[(k4 * 4 + 3) * DIM + c];
#pragma unroll
        for (int r = 0; r < 16; ++r) {
            const float4 xv = A4[r * (DIM / 4) + k4];
            acc[r] = fmaf(xv.x, w0, acc[r]);
            acc[r] = fmaf(xv.y, w1, acc[r]);
            acc[r] = fmaf(xv.z, w2, acc[r]);
            acc[r] = fmaf(xv.w, w3, acc[r]);
        }
    }
    const float bv = half ? 0.f : b_e1[c];
    for (int r = 0; r < 16; ++r)
        U12[(base + r) * 256 + half * 128 + c] = f2bf(acc[r] + bv);
}

// ---------------------------------------------------------------------------
// K8: edges grouped by dst: wave per node. U2[d] register-resident,
//     gather U1[src], relu-add, dot W_e2, shfl reduce, scatter to out[eid].
// ---------------------------------------------------------------------------
__global__ __launch_bounds__(256) void edge_csr(
    const ushort* __restrict__ U12,
    const int* __restrict__ cnt, const int* __restrict__ cursor,
    const uint2* __restrict__ pairs,
    const float* __restrict__ W_e2, const float* __restrict__ b_e2,
    float* __restrict__ out)
{
    const int n = (blockIdx.x * 256 + threadIdx.x) >> 6;
    const int lane = threadIdx.x & 63;
    if (n >= N_NODES) return;

    const int end = cursor[n];
    const int start = end - cnt[n];

    const uint u2b = *(const uint*)(U12 + n * 256 + 128 + lane * 2);
    const float u20 = bf2f(u2b & 0xffffu);
    const float u21 = bf2f(u2b >> 16);
    const float2 w = *(const float2*)&W_e2[lane * 2];
    const float be2 = b_e2[0];

    int i = start;
    for (; i + 2 <= end; i += 2) {
        const uint2 pa = pairs[i];
        const uint2 pb = pairs[i + 1];
        const uint ua = *(const uint*)(U12 + pa.x * 256 + lane * 2);
        const uint ub = *(const uint*)(U12 + pb.x * 256 + lane * 2);
        float p = fmaxf(bf2f(ua & 0xffffu) + u20, 0.f) * w.x
                + fmaxf(bf2f(ua >> 16)     + u21, 0.f) * w.y;
        float q = fmaxf(bf2f(ub & 0xffffu) + u20, 0.f) * w.x
                + fmaxf(bf2f(ub >> 16)     + u21, 0.f) * w.y;
#pragma unroll
        for (int off = 32; off > 0; off >>= 1) {
            p += __shfl_xor(p, off);
            q += __shfl_xor(q, off);
        }
        if (lane == 0) { out[pa.y] = p + be2; out[pb.y] = q + be2; }
    }
    if (i < end) {
        const uint2 pa = pairs[i];
        const uint ua = *(const uint*)(U12 + pa.x * 256 + lane * 2);
        float p = fmaxf(bf2f(ua & 0xffffu) + u20, 0.f) * w.x
                + fmaxf(bf2f(ua >> 16)     + u21, 0.f) * w.y;
#pragma unroll
        for (int off = 32; off > 0; off >>= 1) p += __shfl_xor(p, off);
        if (lane == 0) out[pa.y] = p + be2;
    }
}

// ---------------------------------------------------------------------------
// K9: classifier
// ---------------------------------------------------------------------------
__global__ __launch_bounds__(256) void classify(
    const float* __restrict__ gsum, const float* __restrict__ gcnt,
    const float* __restrict__ W_cls, const float* __restrict__ b_cls,
    float* __restrict__ out)
{
    const int t = threadIdx.x;
    if (t >= N_GRAPHS * N_CLASSES) return;
    const int g = t / N_CLASSES;
    const int c = t % N_CLASSES;
    const float inv = 1.0f / fmaxf(gcnt[g], 1.0f);
    float acc = 0.f;
    for (int k = 0; k < DIM; ++k)
        acc += gsum[g * DIM + k] * W_cls[k * N_CLASSES + c];
    out[g * N_CLASSES + c] = acc * inv + b_cls[c];
}

// ---------------------------------------------------------------------------
extern "C" void kernel_launch(void* const* d_in, const int* in_sizes, int n_in,
                              void* d_out, int out_size, void* d_ws, size_t ws_size,
                              hipStream_t stream)
{
    const float* x      = (const float*)d_in[0];
    const int*   eidx   = (const int*)  d_in[1];
    const int*   bid    = (const int*)  d_in[2];
    const float* W_in   = (const float*)d_in[3];
    const float* W_self = (const float*)d_in[4];
    const float* b      = (const float*)d_in[5];
    const float* W_e1   = (const float*)d_in[6];
    const float* b_e1   = (const float*)d_in[7];
    const float* W_e2   = (const float*)d_in[8];
    const float* b_e2   = (const float*)d_in[9];
    const float* W_cls  = (const float*)d_in[10];
    const float* b_cls  = (const float*)d_in[11];
    float* out = (float*)d_out;

    char* ws = (char*)d_ws;
    int*    cnt    = (int*)   (ws);                       // 40000 B
    float*  gsum   = (float*) (ws + 40960);               // 8192 B
    float*  gcnt   = (float*) (ws + 49152);               // 64 B
    int*    cursor = (int*)   (ws + 65536);               // 40000 B
    uint2*  pairs  = (uint2*) (ws + 131072);              // 5,120,000 B
    float*  XAGG   = (float*) (ws + 131072 + 5120000);    // 5,120,000 B (becomes z)
    ushort* U12    = (ushort*)(ws + 131072 + 10240000);   // 5,120,000 B

    const int* src = eidx;
    const int* dst = eidx + N_EDGES;

    hipMemsetAsync(d_ws, 0, 65536, stream);   // cnt + gsum + gcnt

    hist_dst   <<<N_EDGES / 256, 256, 0, stream>>>(dst, cnt);
    count_nodes<<<1, 256, 0, stream>>>(bid, gcnt);
    scan_k     <<<1, 1024, 0, stream>>>(cnt, cursor);
    fill_csr   <<<N_EDGES / 256, 256, 0, stream>>>(src, dst, cursor, pairs);
    gather_x   <<<N_NODES / 2, 256, 0, stream>>>(x, cnt, cursor, pairs, XAGG);
    gemm_z     <<<N_NODES / 16, 256, 0, stream>>>(XAGG, x, W_in, W_self, b, bid, XAGG, gsum);
    gemm_u12   <<<N_NODES / 16, 256, 0, stream>>>(XAGG, W_e1, b_e1, U12);
    edge_csr   <<<(N_NODES * 64) / 256, 256, 0, stream>>>(U12, cnt, cursor, pairs, W_e2, b_e2, out);
    classify   <<<1, 256, 0, stream>>>(gsum, gcnt, W_cls, b_cls, out + N_EDGES);
}

// Round 11
// 318.132 us; speedup vs baseline: 2.0513x; 1.0343x over previous
//
#include <hip/hip_runtime.h>

#define N_NODES   10000
#define N_EDGES   640000
#define DIM       128
#define N_GRAPHS  16
#define N_CLASSES 10

typedef unsigned int uint;
typedef unsigned short ushort;

__device__ __forceinline__ float bf2f(uint lo16) {
    return __uint_as_float(lo16 << 16);
}
__device__ __forceinline__ ushort f2bf(float f) {
    uint u = __float_as_uint(f);
    u += 0x7fffu + ((u >> 16) & 1u);      // round-to-nearest-even
    return (ushort)(u >> 16);
}

// ---------------------------------------------------------------------------
// K1: histogram of dst
// ---------------------------------------------------------------------------
__global__ __launch_bounds__(256) void hist_dst(
    const int* __restrict__ dst, int* __restrict__ cnt)
{
    const int e = blockIdx.x * 256 + threadIdx.x;
    if (e < N_EDGES) atomicAdd(&cnt[dst[e]], 1);
}

// ---------------------------------------------------------------------------
// K2: per-graph node counts (batch_ids) -> gcnt (float)
// ---------------------------------------------------------------------------
__global__ __launch_bounds__(256) void count_nodes(
    const int* __restrict__ bid, float* __restrict__ gcnt)
{
    __shared__ int h[N_GRAPHS];
    const int t = threadIdx.x;
    if (t < N_GRAPHS) h[t] = 0;
    __syncthreads();
    for (int n = t; n < N_NODES; n += 256) atomicAdd(&h[bid[n]], 1);
    __syncthreads();
    if (t < N_GRAPHS) gcnt[t] = (float)h[t];
}

// ---------------------------------------------------------------------------
// K3: exclusive prefix sum of cnt[10000] -> cursor (single block)
// ---------------------------------------------------------------------------
__global__ __launch_bounds__(1024) void scan_k(
    const int* __restrict__ cnt, int* __restrict__ cursor)
{
    __shared__ int s[1024];
    const int t = threadIdx.x;
    int local[10];
    int sum = 0;
    if (t < 1000) {
        for (int j = 0; j < 10; ++j) { local[j] = sum; sum += cnt[t * 10 + j]; }
    }
    s[t] = (t < 1000) ? sum : 0;
    __syncthreads();
    for (int st = 1; st < 1024; st <<= 1) {
        int v = (t >= st) ? s[t - st] : 0;
        __syncthreads();
        s[t] += v;
        __syncthreads();
    }
    if (t < 1000) {
        const int off = (t == 0) ? 0 : s[t - 1];
        for (int j = 0; j < 10; ++j) cursor[t * 10 + j] = off + local[j];
    }
}

// ---------------------------------------------------------------------------
// K4: fill CSR: srcs[pos] = src, grouped by dst.
// After this kernel cursor[d] == segment end (start = end - cnt[d]).
// ---------------------------------------------------------------------------
__global__ __launch_bounds__(256) void fill_csr(
    const int* __restrict__ src, const int* __restrict__ dst,
    int* __restrict__ cursor, uint* __restrict__ srcs)
{
    const int e = blockIdx.x * 256 + threadIdx.x;
    if (e < N_EDGES) {
        const int pos = atomicAdd(&cursor[dst[e]], 1);
        srcs[pos] = (uint)src[e];
    }
}

// ---------------------------------------------------------------------------
// K5: XAGG[d] = sum over in-edges of x[src]. Wave per node, lane = float2.
// ---------------------------------------------------------------------------
__global__ __launch_bounds__(256) void gather_x(
    const float* __restrict__ x,
    const int* __restrict__ cnt, const int* __restrict__ cursor,
    const uint* __restrict__ srcs,
    float* __restrict__ XAGG)
{
    const int n    = blockIdx.x * 4 + (threadIdx.x >> 6);
    const int lane = threadIdx.x & 63;
    const int end  = cursor[n];
    int i = end - cnt[n];

    float2 a0 = {0.f, 0.f}, a1 = {0.f, 0.f}, a2 = {0.f, 0.f}, a3 = {0.f, 0.f};
    const int co = lane * 2;

    for (; i + 4 <= end; i += 4) {
        const uint s0 = srcs[i], s1 = srcs[i + 1], s2 = srcs[i + 2], s3 = srcs[i + 3];
        const float2 r0 = *(const float2*)&x[s0 * DIM + co];
        const float2 r1 = *(const float2*)&x[s1 * DIM + co];
        const float2 r2 = *(const float2*)&x[s2 * DIM + co];
        const float2 r3 = *(const float2*)&x[s3 * DIM + co];
        a0.x += r0.x; a0.y += r0.y;
        a1.x += r1.x; a1.y += r1.y;
        a2.x += r2.x; a2.y += r2.y;
        a3.x += r3.x; a3.y += r3.y;
    }
    for (; i < end; ++i) {
        const float2 r = *(const float2*)&x[srcs[i] * DIM + co];
        a0.x += r.x; a0.y += r.y;
    }
    float2 s;
    s.x = (a0.x + a1.x) + (a2.x + a3.x);
    s.y = (a0.y + a1.y) + (a2.y + a3.y);
    *(float2*)&XAGG[n * DIM + co] = s;
}

// ---------------------------------------------------------------------------
// K6: z = relu(XAGG@W_in + x@W_self + b)  (in place over XAGG)
//     + per-graph sums via run-compressed atomics (batch_ids sorted)
// ---------------------------------------------------------------------------
__global__ __launch_bounds__(256) void gemm_z(
    const float* __restrict__ XAGG_in, const float* __restrict__ x,
    const float* __restrict__ W_in, const float* __restrict__ W_self,
    const float* __restrict__ b, const int* __restrict__ bid,
    float* __restrict__ Z, float* __restrict__ gsum)
{
    __shared__ float sa[16 * DIM];
    __shared__ float sb[16 * DIM];
    __shared__ int sbid[16];
    const int base = blockIdx.x * 16;
    const int t = threadIdx.x;
    {
        const float4* ga = (const float4*)(XAGG_in + base * DIM);
        const float4* gb = (const float4*)(x + base * DIM);
        float4* la = (float4*)sa;
        float4* lb = (float4*)sb;
        for (int i = t; i < 16 * DIM / 4; i += 256) { la[i] = ga[i]; lb[i] = gb[i]; }
        if (t < 16) sbid[t] = bid[base + t];
    }
    __syncthreads();

    const int half = t >> 7, c = t & 127;
    const float* __restrict__ W = half ? W_self : W_in;
    const float4* A4 = (const float4*)(half ? sb : sa);

    float acc[16];
#pragma unroll
    for (int r = 0; r < 16; ++r) acc[r] = 0.f;

    for (int k4 = 0; k4 < DIM / 4; ++k4) {
        const float w0 = W[(k4 * 4 + 0) * DIM + c];
        const float w1 = W[(k4 * 4 + 1) * DIM + c];
        const float w2 = W[(k4 * 4 + 2) * DIM + c];
        const float w3 = W[(k4 * 4 + 3) * DIM + c];
#pragma unroll
        for (int r = 0; r < 16; ++r) {
            const float4 xv = A4[r * (DIM / 4) + k4];
            acc[r] = fmaf(xv.x, w0, acc[r]);
            acc[r] = fmaf(xv.y, w1, acc[r]);
            acc[r] = fmaf(xv.z, w2, acc[r]);
            acc[r] = fmaf(xv.w, w3, acc[r]);
        }
    }
    __syncthreads();
    if (half) {
#pragma unroll
        for (int r = 0; r < 16; ++r) sa[r * DIM + c] = acc[r];
    }
    __syncthreads();
    if (!half) {
        const float bv = b[c];
        float run = 0.f;
        int cur = sbid[0];
#pragma unroll
        for (int r = 0; r < 16; ++r) {
            const float z = fmaxf(acc[r] + sa[r * DIM + c] + bv, 0.f);
            Z[(base + r) * DIM + c] = z;
            const int g = sbid[r];
            if (g != cur) { unsafeAtomicAdd(&gsum[cur * DIM + c], run); run = 0.f; cur = g; }
            run += z;
        }
        unsafeAtomicAdd(&gsum[cur * DIM + c], run);
    }
}

// ---------------------------------------------------------------------------
// K7: U12 = z @ [W_e1_top | W_e1_bot] (+b_e1 on U1 half), bf16 interleaved
// ---------------------------------------------------------------------------
__global__ __launch_bounds__(256) void gemm_u12(
    const float* __restrict__ Z,
    const float* __restrict__ W_e1, const float* __restrict__ b_e1,
    ushort* __restrict__ U12)
{
    __shared__ float xs[16 * DIM];
    const int base = blockIdx.x * 16;
    const int t = threadIdx.x;
    {
        const float4* g = (const float4*)(Z + base * DIM);
        float4* l = (float4*)xs;
        for (int i = t; i < 16 * DIM / 4; i += 256) l[i] = g[i];
    }
    __syncthreads();

    const int half = t >> 7, c = t & 127;
    const float* __restrict__ W = W_e1 + half * 128 * DIM;
    const float4* A4 = (const float4*)xs;

    float acc[16];
#pragma unroll
    for (int r = 0; r < 16; ++r) acc[r] = 0.f;

    for (int k4 = 0; k4 < DIM / 4; ++k4) {
        const float w0 = W[(k4 * 4 + 0) * DIM + c];
        const float w1 = W[(k4 * 4 + 1) * DIM + c];
        const float w2 = W[(k4 * 4 + 2) * DIM + c];
        const float w3 = W[(k4 * 4 + 3) * DIM + c];
#pragma unroll
        for (int r = 0; r < 16; ++r) {
            const float4 xv = A4[r * (DIM / 4) + k4];
            acc[r] = fmaf(xv.x, w0, acc[r]);
            acc[r] = fmaf(xv.y, w1, acc[r]);
            acc[r] = fmaf(xv.z, w2, acc[r]);
            acc[r] = fmaf(xv.w, w3, acc[r]);
        }
    }
    const float bv = half ? 0.f : b_e1[c];
    for (int r = 0; r < 16; ++r)
        U12[(base + r) * 256 + half * 128 + c] = f2bf(acc[r] + bv);
}

// ---------------------------------------------------------------------------
// K8: lane-per-edge, natural order: out[e] = relu(U1[src]+U2[dst]).W_e2 + b_e2
// U12 row: [U1[0..127] | U2[0..127]] bf16. W_e2 broadcast from LDS.
// ---------------------------------------------------------------------------
__device__ __forceinline__ void ch2(uint a, uint b, float wl, float wh,
                                    float& accl, float& acch)
{
    const float fl = fmaxf(__uint_as_float(a << 16) + __uint_as_float(b << 16), 0.f);
    const float fh = fmaxf(__uint_as_float(a & 0xffff0000u) + __uint_as_float(b & 0xffff0000u), 0.f);
    accl = fmaf(fl, wl, accl);
    acch = fmaf(fh, wh, acch);
}

__global__ __launch_bounds__(256) void edge_mlp2(
    const ushort* __restrict__ U12,
    const int* __restrict__ src, const int* __restrict__ dst,
    const float* __restrict__ W_e2, const float* __restrict__ b_e2,
    float* __restrict__ out)
{
    __shared__ float ws[DIM];
    const int t = threadIdx.x;
    if (t < DIM) ws[t] = W_e2[t];
    __syncthreads();

    const int e = blockIdx.x * 256 + t;   // N_EDGES = 2500*256 exactly
    const int s = src[e];
    const int d = dst[e];

    const uint4* __restrict__ u1p = (const uint4*)(U12 + s * 256);
    const uint4* __restrict__ u2p = (const uint4*)(U12 + d * 256 + 128);
    const float4* __restrict__ wp = (const float4*)ws;

    float acc0 = 0.f, acc1 = 0.f;
#pragma unroll
    for (int c = 0; c < 16; ++c) {
        const uint4 a  = u1p[c];
        const uint4 bv = u2p[c];
        const float4 w0 = wp[c * 2 + 0];
        const float4 w1 = wp[c * 2 + 1];
        ch2(a.x, bv.x, w0.x, w0.y, acc0, acc1);
        ch2(a.y, bv.y, w0.z, w0.w, acc0, acc1);
        ch2(a.z, bv.z, w1.x, w1.y, acc0, acc1);
        ch2(a.w, bv.w, w1.z, w1.w, acc0, acc1);
    }
    out[e] = acc0 + acc1 + b_e2[0];
}

// ---------------------------------------------------------------------------
// K9: classifier
// ---------------------------------------------------------------------------
__global__ __launch_bounds__(256) void classify(
    const float* __restrict__ gsum, const float* __restrict__ gcnt,
    const float* __restrict__ W_cls, const float* __restrict__ b_cls,
    float* __restrict__ out)
{
    const int t = threadIdx.x;
    if (t >= N_GRAPHS * N_CLASSES) return;
    const int g = t / N_CLASSES;
    const int c = t % N_CLASSES;
    const float inv = 1.0f / fmaxf(gcnt[g], 1.0f);
    float acc = 0.f;
    for (int k = 0; k < DIM; ++k)
        acc += gsum[g * DIM + k] * W_cls[k * N_CLASSES + c];
    out[g * N_CLASSES + c] = acc * inv + b_cls[c];
}

// ---------------------------------------------------------------------------
extern "C" void kernel_launch(void* const* d_in, const int* in_sizes, int n_in,
                              void* d_out, int out_size, void* d_ws, size_t ws_size,
                              hipStream_t stream)
{
    const float* x      = (const float*)d_in[0];
    const int*   eidx   = (const int*)  d_in[1];
    const int*   bid    = (const int*)  d_in[2];
    const float* W_in   = (const float*)d_in[3];
    const float* W_self = (const float*)d_in[4];
    const float* b      = (const float*)d_in[5];
    const float* W_e1   = (const float*)d_in[6];
    const float* b_e1   = (const float*)d_in[7];
    const float* W_e2   = (const float*)d_in[8];
    const float* b_e2   = (const float*)d_in[9];
    const float* W_cls  = (const float*)d_in[10];
    const float* b_cls  = (const float*)d_in[11];
    float* out = (float*)d_out;

    char* ws = (char*)d_ws;
    int*    cnt    = (int*)   (ws);                        // 40000 B
    float*  gsum   = (float*) (ws + 40960);                // 8192 B
    float*  gcnt   = (float*) (ws + 49152);                // 64 B
    int*    cursor = (int*)   (ws + 65536);                // 40000 B
    uint*   srcs   = (uint*)  (ws + 131072);               // 2,560,000 B
    float*  XAGG   = (float*) (ws + 131072 + 2560000);     // 5,120,000 B (becomes z)
    ushort* U12    = (ushort*)(ws + 131072 + 7680000);     // 5,120,000 B

    const int* src = eidx;
    const int* dst = eidx + N_EDGES;

    hipMemsetAsync(d_ws, 0, 65536, stream);   // cnt + gsum + gcnt

    hist_dst   <<<N_EDGES / 256, 256, 0, stream>>>(dst, cnt);
    count_nodes<<<1, 256, 0, stream>>>(bid, gcnt);
    scan_k     <<<1, 1024, 0, stream>>>(cnt, cursor);
    fill_csr   <<<N_EDGES / 256, 256, 0, stream>>>(src, dst, cursor, srcs);
    gather_x   <<<N_NODES / 4, 256, 0, stream>>>(x, cnt, cursor, srcs, XAGG);
    gemm_z     <<<N_NODES / 16, 256, 0, stream>>>(XAGG, x, W_in, W_self, b, bid, XAGG, gsum);
    gemm_u12   <<<N_NODES / 16, 256, 0, stream>>>(XAGG, W_e1, b_e1, U12);
    edge_mlp2  <<<N_EDGES / 256, 256, 0, stream>>>(U12, src, dst, W_e2, b_e2, out);
    classify   <<<1, 256, 0, stream>>>(gsum, gcnt, W_cls, b_cls, out + N_EDGES);
}

// Round 12
// 295.111 us; speedup vs baseline: 2.2113x; 1.0780x over previous
//
#include <hip/hip_runtime.h>

#define N_NODES   10000
#define N_EDGES   640000
#define DIM       128
#define N_GRAPHS  16
#define N_CLASSES 10

typedef unsigned int uint;
typedef unsigned short ushort;

__device__ __forceinline__ float bf2f(uint lo16) {
    return __uint_as_float(lo16 << 16);
}
__device__ __forceinline__ ushort f2bf(float f) {
    uint u = __float_as_uint(f);
    u += 0x7fffu + ((u >> 16) & 1u);      // round-to-nearest-even
    return (ushort)(u >> 16);
}

// ---------------------------------------------------------------------------
// K1: histogram of dst
// ---------------------------------------------------------------------------
__global__ __launch_bounds__(256) void hist_dst(
    const int* __restrict__ dst, int* __restrict__ cnt)
{
    const int e = blockIdx.x * 256 + threadIdx.x;
    if (e < N_EDGES) atomicAdd(&cnt[dst[e]], 1);
}

// ---------------------------------------------------------------------------
// K2: per-graph node counts (batch_ids) -> gcnt (float)
// ---------------------------------------------------------------------------
__global__ __launch_bounds__(256) void count_nodes(
    const int* __restrict__ bid, float* __restrict__ gcnt)
{
    __shared__ int h[N_GRAPHS];
    const int t = threadIdx.x;
    if (t < N_GRAPHS) h[t] = 0;
    __syncthreads();
    for (int n = t; n < N_NODES; n += 256) atomicAdd(&h[bid[n]], 1);
    __syncthreads();
    if (t < N_GRAPHS) gcnt[t] = (float)h[t];
}

// ---------------------------------------------------------------------------
// K3: exclusive prefix sum of cnt[10000] -> cursor (single block)
// ---------------------------------------------------------------------------
__global__ __launch_bounds__(1024) void scan_k(
    const int* __restrict__ cnt, int* __restrict__ cursor)
{
    __shared__ int s[1024];
    const int t = threadIdx.x;
    int local[10];
    int sum = 0;
    if (t < 1000) {
        for (int j = 0; j < 10; ++j) { local[j] = sum; sum += cnt[t * 10 + j]; }
    }
    s[t] = (t < 1000) ? sum : 0;
    __syncthreads();
    for (int st = 1; st < 1024; st <<= 1) {
        int v = (t >= st) ? s[t - st] : 0;
        __syncthreads();
        s[t] += v;
        __syncthreads();
    }
    if (t < 1000) {
        const int off = (t == 0) ? 0 : s[t - 1];
        for (int j = 0; j < 10; ++j) cursor[t * 10 + j] = off + local[j];
    }
}

// ---------------------------------------------------------------------------
// K4: fill CSR: srcs[pos] = src, grouped by dst.
// ---------------------------------------------------------------------------
__global__ __launch_bounds__(256) void fill_csr(
    const int* __restrict__ src, const int* __restrict__ dst,
    int* __restrict__ cursor, uint* __restrict__ srcs)
{
    const int e = blockIdx.x * 256 + threadIdx.x;
    if (e < N_EDGES) {
        const int pos = atomicAdd(&cursor[dst[e]], 1);
        srcs[pos] = (uint)src[e];
    }
}

// ---------------------------------------------------------------------------
// K5: XAGG[d] = sum over in-edges of x[src]. Wave per node, lane = float2.
// ---------------------------------------------------------------------------
__global__ __launch_bounds__(256) void gather_x(
    const float* __restrict__ x,
    const int* __restrict__ cnt, const int* __restrict__ cursor,
    const uint* __restrict__ srcs,
    float* __restrict__ XAGG)
{
    const int n    = blockIdx.x * 4 + (threadIdx.x >> 6);
    const int lane = threadIdx.x & 63;
    const int end  = cursor[n];
    int i = end - cnt[n];

    float2 a0 = {0.f, 0.f}, a1 = {0.f, 0.f}, a2 = {0.f, 0.f}, a3 = {0.f, 0.f};
    const int co = lane * 2;

    for (; i + 4 <= end; i += 4) {
        const uint s0 = srcs[i], s1 = srcs[i + 1], s2 = srcs[i + 2], s3 = srcs[i + 3];
        const float2 r0 = *(const float2*)&x[s0 * DIM + co];
        const float2 r1 = *(const float2*)&x[s1 * DIM + co];
        const float2 r2 = *(const float2*)&x[s2 * DIM + co];
        const float2 r3 = *(const float2*)&x[s3 * DIM + co];
        a0.x += r0.x; a0.y += r0.y;
        a1.x += r1.x; a1.y += r1.y;
        a2.x += r2.x; a2.y += r2.y;
        a3.x += r3.x; a3.y += r3.y;
    }
    for (; i < end; ++i) {
        const float2 r = *(const float2*)&x[srcs[i] * DIM + co];
        a0.x += r.x; a0.y += r.y;
    }
    float2 s;
    s.x = (a0.x + a1.x) + (a2.x + a3.x);
    s.y = (a0.y + a1.y) + (a2.y + a3.y);
    *(float2*)&XAGG[n * DIM + co] = s;
}

// ---------------------------------------------------------------------------
// K6: z = relu(XAGG@W_in + x@W_self + b)  (in place over XAGG)
//     + per-graph sums via run-compressed atomics (batch_ids sorted)
// ---------------------------------------------------------------------------
__global__ __launch_bounds__(256) void gemm_z(
    const float* __restrict__ XAGG_in, const float* __restrict__ x,
    const float* __restrict__ W_in, const float* __restrict__ W_self,
    const float* __restrict__ b, const int* __restrict__ bid,
    float* __restrict__ Z, float* __restrict__ gsum)
{
    __shared__ float sa[16 * DIM];
    __shared__ float sb[16 * DIM];
    __shared__ int sbid[16];
    const int base = blockIdx.x * 16;
    const int t = threadIdx.x;
    {
        const float4* ga = (const float4*)(XAGG_in + base * DIM);
        const float4* gb = (const float4*)(x + base * DIM);
        float4* la = (float4*)sa;
        float4* lb = (float4*)sb;
        for (int i = t; i < 16 * DIM / 4; i += 256) { la[i] = ga[i]; lb[i] = gb[i]; }
        if (t < 16) sbid[t] = bid[base + t];
    }
    __syncthreads();

    const int half = t >> 7, c = t & 127;
    const float* __restrict__ W = half ? W_self : W_in;
    const float4* A4 = (const float4*)(half ? sb : sa);

    float acc[16];
#pragma unroll
    for (int r = 0; r < 16; ++r) acc[r] = 0.f;

    for (int k4 = 0; k4 < DIM / 4; ++k4) {
        const float w0 = W[(k4 * 4 + 0) * DIM + c];
        const float w1 = W[(k4 * 4 + 1) * DIM + c];
        const float w2 = W[(k4 * 4 + 2) * DIM + c];
        const float w3 = W[(k4 * 4 + 3) * DIM + c];
#pragma unroll
        for (int r = 0; r < 16; ++r) {
            const float4 xv = A4[r * (DIM / 4) + k4];
            acc[r] = fmaf(xv.x, w0, acc[r]);
            acc[r] = fmaf(xv.y, w1, acc[r]);
            acc[r] = fmaf(xv.z, w2, acc[r]);
            acc[r] = fmaf(xv.w, w3, acc[r]);
        }
    }
    __syncthreads();
    if (half) {
#pragma unroll
        for (int r = 0; r < 16; ++r) sa[r * DIM + c] = acc[r];
    }
    __syncthreads();
    if (!half) {
        const float bv = b[c];
        float run = 0.f;
        int cur = sbid[0];
#pragma unroll
        for (int r = 0; r < 16; ++r) {
            const float z = fmaxf(acc[r] + sa[r * DIM + c] + bv, 0.f);
            Z[(base + r) * DIM + c] = z;
            const int g = sbid[r];
            if (g != cur) { unsafeAtomicAdd(&gsum[cur * DIM + c], run); run = 0.f; cur = g; }
            run += z;
        }
        unsafeAtomicAdd(&gsum[cur * DIM + c], run);
    }
}

// ---------------------------------------------------------------------------
// K7: U12 = z @ [W_e1_top | W_e1_bot] (+b_e1 on U1 half), bf16 interleaved
// ---------------------------------------------------------------------------
__global__ __launch_bounds__(256) void gemm_u12(
    const float* __restrict__ Z,
    const float* __restrict__ W_e1, const float* __restrict__ b_e1,
    ushort* __restrict__ U12)
{
    __shared__ float xs[16 * DIM];
    const int base = blockIdx.x * 16;
    const int t = threadIdx.x;
    {
        const float4* g = (const float4*)(Z + base * DIM);
        float4* l = (float4*)xs;
        for (int i = t; i < 16 * DIM / 4; i += 256) l[i] = g[i];
    }
    __syncthreads();

    const int half = t >> 7, c = t & 127;
    const float* __restrict__ W = W_e1 + half * 128 * DIM;
    const float4* A4 = (const float4*)xs;

    float acc[16];
#pragma unroll
    for (int r = 0; r < 16; ++r) acc[r] = 0.f;

    for (int k4 = 0; k4 < DIM / 4; ++k4) {
        const float w0 = W[(k4 * 4 + 0) * DIM + c];
        const float w1 = W[(k4 * 4 + 1) * DIM + c];
        const float w2 = W[(k4 * 4 + 2) * DIM + c];
        const float w3 = W[(k4 * 4 + 3) * DIM + c];
#pragma unroll
        for (int r = 0; r < 16; ++r) {
            const float4 xv = A4[r * (DIM / 4) + k4];
            acc[r] = fmaf(xv.x, w0, acc[r]);
            acc[r] = fmaf(xv.y, w1, acc[r]);
            acc[r] = fmaf(xv.z, w2, acc[r]);
            acc[r] = fmaf(xv.w, w3, acc[r]);
        }
    }
    const float bv = half ? 0.f : b_e1[c];
    for (int r = 0; r < 16; ++r)
        U12[(base + r) * 256 + half * 128 + c] = f2bf(acc[r] + bv);
}

// ---------------------------------------------------------------------------
// K8: 16 lanes per edge, coalesced row reads.
// Each 16-lane group: lane l16 handles channels [l16*8, l16*8+8) of one edge.
// u1/u2 row reads are contiguous 256B per group -> 16x fewer scattered lines
// than lane-per-edge. 4-step shfl_xor reduce within group; l16==0 stores.
// ---------------------------------------------------------------------------
__device__ __forceinline__ void ch2(uint a, uint b, float wl, float wh,
                                    float& accl, float& acch)
{
    const float fl = fmaxf(__uint_as_float(a << 16) + __uint_as_float(b << 16), 0.f);
    const float fh = fmaxf(__uint_as_float(a & 0xffff0000u) + __uint_as_float(b & 0xffff0000u), 0.f);
    accl = fmaf(fl, wl, accl);
    acch = fmaf(fh, wh, acch);
}

__global__ __launch_bounds__(256) void edge_mlp3(
    const ushort* __restrict__ U12,
    const int* __restrict__ src, const int* __restrict__ dst,
    const float* __restrict__ W_e2, const float* __restrict__ b_e2,
    float* __restrict__ out)
{
    __shared__ float ws[DIM];
    const int t = threadIdx.x;
    if (t < DIM) ws[t] = W_e2[t];
    __syncthreads();

    const int l16  = t & 15;                       // lane within 16-lane group
    const int grp  = t >> 4;                       // group within block (0..15)
    const int e    = blockIdx.x * 16 + grp;        // 16 edges per block; grid = 40000

    const int s = src[e];
    const int d = dst[e];

    // lane's 8 channels of U1[src] and U2[dst] (16B contiguous per lane;
    // 256B contiguous per 16-lane group)
    const uint4 a  = *(const uint4*)(U12 + s * 256 + l16 * 8);
    const uint4 bv = *(const uint4*)(U12 + d * 256 + 128 + l16 * 8);
    const float4 w0 = ((const float4*)ws)[l16 * 2 + 0];
    const float4 w1 = ((const float4*)ws)[l16 * 2 + 1];

    float acc0 = 0.f, acc1 = 0.f;
    ch2(a.x, bv.x, w0.x, w0.y, acc0, acc1);
    ch2(a.y, bv.y, w0.z, w0.w, acc0, acc1);
    ch2(a.z, bv.z, w1.x, w1.y, acc0, acc1);
    ch2(a.w, bv.w, w1.z, w1.w, acc0, acc1);

    float p = acc0 + acc1;
#pragma unroll
    for (int off = 8; off >= 1; off >>= 1)
        p += __shfl_xor(p, off);                   // reduce within 16-lane group

    if (l16 == 0) out[e] = p + b_e2[0];
}

// ---------------------------------------------------------------------------
// K9: classifier
// ---------------------------------------------------------------------------
__global__ __launch_bounds__(256) void classify(
    const float* __restrict__ gsum, const float* __restrict__ gcnt,
    const float* __restrict__ W_cls, const float* __restrict__ b_cls,
    float* __restrict__ out)
{
    const int t = threadIdx.x;
    if (t >= N_GRAPHS * N_CLASSES) return;
    const int g = t / N_CLASSES;
    const int c = t % N_CLASSES;
    const float inv = 1.0f / fmaxf(gcnt[g], 1.0f);
    float acc = 0.f;
    for (int k = 0; k < DIM; ++k)
        acc += gsum[g * DIM + k] * W_cls[k * N_CLASSES + c];
    out[g * N_CLASSES + c] = acc * inv + b_cls[c];
}

// ---------------------------------------------------------------------------
extern "C" void kernel_launch(void* const* d_in, const int* in_sizes, int n_in,
                              void* d_out, int out_size, void* d_ws, size_t ws_size,
                              hipStream_t stream)
{
    const float* x      = (const float*)d_in[0];
    const int*   eidx   = (const int*)  d_in[1];
    const int*   bid    = (const int*)  d_in[2];
    const float* W_in   = (const float*)d_in[3];
    const float* W_self = (const float*)d_in[4];
    const float* b      = (const float*)d_in[5];
    const float* W_e1   = (const float*)d_in[6];
    const float* b_e1   = (const float*)d_in[7];
    const float* W_e2   = (const float*)d_in[8];
    const float* b_e2   = (const float*)d_in[9];
    const float* W_cls  = (const float*)d_in[10];
    const float* b_cls  = (const float*)d_in[11];
    float* out = (float*)d_out;

    char* ws = (char*)d_ws;
    int*    cnt    = (int*)   (ws);                        // 40000 B
    float*  gsum   = (float*) (ws + 40960);                // 8192 B
    float*  gcnt   = (float*) (ws + 49152);                // 64 B
    int*    cursor = (int*)   (ws + 65536);                // 40000 B
    uint*   srcs   = (uint*)  (ws + 131072);               // 2,560,000 B
    float*  XAGG   = (float*) (ws + 131072 + 2560000);     // 5,120,000 B (becomes z)
    ushort* U12    = (ushort*)(ws + 131072 + 7680000);     // 5,120,000 B

    const int* src = eidx;
    const int* dst = eidx + N_EDGES;

    hipMemsetAsync(d_ws, 0, 65536, stream);   // cnt + gsum + gcnt

    hist_dst   <<<N_EDGES / 256, 256, 0, stream>>>(dst, cnt);
    count_nodes<<<1, 256, 0, stream>>>(bid, gcnt);
    scan_k     <<<1, 1024, 0, stream>>>(cnt, cursor);
    fill_csr   <<<N_EDGES / 256, 256, 0, stream>>>(src, dst, cursor, srcs);
    gather_x   <<<N_NODES / 4, 256, 0, stream>>>(x, cnt, cursor, srcs, XAGG);
    gemm_z     <<<N_NODES / 16, 256, 0, stream>>>(XAGG, x, W_in, W_self, b, bid, XAGG, gsum);
    gemm_u12   <<<N_NODES / 16, 256, 0, stream>>>(XAGG, W_e1, b_e1, U12);
    edge_mlp3  <<<N_EDGES / 16, 256, 0, stream>>>(U12, src, dst, W_e2, b_e2, out);
    classify   <<<1, 256, 0, stream>>>(gsum, gcnt, W_cls, b_cls, out + N_EDGES);
}

// Round 14
// 293.445 us; speedup vs baseline: 2.2239x; 1.0057x over previous
//
#include <hip/hip_runtime.h>

#define N_NODES   10000
#define N_EDGES   640000
#define DIM       128
#define N_GRAPHS  16
#define N_CLASSES 10

typedef unsigned int uint;
typedef unsigned short ushort;

__device__ __forceinline__ float bf2f(uint lo16) {
    return __uint_as_float(lo16 << 16);
}
__device__ __forceinline__ ushort f2bf(float f) {
    uint u = __float_as_uint(f);
    u += 0x7fffu + ((u >> 16) & 1u);      // round-to-nearest-even
    return (ushort)(u >> 16);
}

// ---------------------------------------------------------------------------
// K1: histogram of dst — 4 edges/thread, independent atomic chains
// ---------------------------------------------------------------------------
__global__ __launch_bounds__(256) void hist_dst(
    const int* __restrict__ dst, int* __restrict__ cnt)
{
    const int base = (blockIdx.x * 256 + threadIdx.x) * 4;   // 625 blocks exact
    const int d0 = dst[base + 0];
    const int d1 = dst[base + 1];
    const int d2 = dst[base + 2];
    const int d3 = dst[base + 3];
    atomicAdd(&cnt[d0], 1);
    atomicAdd(&cnt[d1], 1);
    atomicAdd(&cnt[d2], 1);
    atomicAdd(&cnt[d3], 1);
}

// ---------------------------------------------------------------------------
// K2: per-graph node counts (batch_ids) -> gcnt (float)
// ---------------------------------------------------------------------------
__global__ __launch_bounds__(256) void count_nodes(
    const int* __restrict__ bid, float* __restrict__ gcnt)
{
    __shared__ int h[N_GRAPHS];
    const int t = threadIdx.x;
    if (t < N_GRAPHS) h[t] = 0;
    __syncthreads();
    for (int n = t; n < N_NODES; n += 256) atomicAdd(&h[bid[n]], 1);
    __syncthreads();
    if (t < N_GRAPHS) gcnt[t] = (float)h[t];
}

// ---------------------------------------------------------------------------
// K3: exclusive prefix sum of cnt[10000] -> cursor (single block)
// ---------------------------------------------------------------------------
__global__ __launch_bounds__(1024) void scan_k(
    const int* __restrict__ cnt, int* __restrict__ cursor)
{
    __shared__ int s[1024];
    const int t = threadIdx.x;
    int local[10];
    int sum = 0;
    if (t < 1000) {
        for (int j = 0; j < 10; ++j) { local[j] = sum; sum += cnt[t * 10 + j]; }
    }
    s[t] = (t < 1000) ? sum : 0;
    __syncthreads();
    for (int st = 1; st < 1024; st <<= 1) {
        int v = (t >= st) ? s[t - st] : 0;
        __syncthreads();
        s[t] += v;
        __syncthreads();
    }
    if (t < 1000) {
        const int off = (t == 0) ? 0 : s[t - 1];
        for (int j = 0; j < 10; ++j) cursor[t * 10 + j] = off + local[j];
    }
}

// ---------------------------------------------------------------------------
// K4: fill CSR — 4 edges/thread, 4 independent atomic->store chains
// ---------------------------------------------------------------------------
__global__ __launch_bounds__(256) void fill_csr(
    const int* __restrict__ src, const int* __restrict__ dst,
    int* __restrict__ cursor, uint* __restrict__ srcs)
{
    const int base = (blockIdx.x * 256 + threadIdx.x) * 4;   // 625 blocks exact
    const int d0 = dst[base + 0];
    const int d1 = dst[base + 1];
    const int d2 = dst[base + 2];
    const int d3 = dst[base + 3];
    const int s0 = src[base + 0];
    const int s1 = src[base + 1];
    const int s2 = src[base + 2];
    const int s3 = src[base + 3];
    const int p0 = atomicAdd(&cursor[d0], 1);
    const int p1 = atomicAdd(&cursor[d1], 1);
    const int p2 = atomicAdd(&cursor[d2], 1);
    const int p3 = atomicAdd(&cursor[d3], 1);
    srcs[p0] = (uint)s0;
    srcs[p1] = (uint)s1;
    srcs[p2] = (uint)s2;
    srcs[p3] = (uint)s3;
}

// ---------------------------------------------------------------------------
// K5: XAGG[d] = sum over in-edges of x[src]. Wave per node, lane = float2.
// ---------------------------------------------------------------------------
__global__ __launch_bounds__(256) void gather_x(
    const float* __restrict__ x,
    const int* __restrict__ cnt, const int* __restrict__ cursor,
    const uint* __restrict__ srcs,
    float* __restrict__ XAGG)
{
    const int n    = blockIdx.x * 4 + (threadIdx.x >> 6);
    const int lane = threadIdx.x & 63;
    const int end  = cursor[n];
    int i = end - cnt[n];

    float2 a0 = {0.f, 0.f}, a1 = {0.f, 0.f}, a2 = {0.f, 0.f}, a3 = {0.f, 0.f};
    const int co = lane * 2;

    for (; i + 4 <= end; i += 4) {
        const uint s0 = srcs[i], s1 = srcs[i + 1], s2 = srcs[i + 2], s3 = srcs[i + 3];
        const float2 r0 = *(const float2*)&x[s0 * DIM + co];
        const float2 r1 = *(const float2*)&x[s1 * DIM + co];
        const float2 r2 = *(const float2*)&x[s2 * DIM + co];
        const float2 r3 = *(const float2*)&x[s3 * DIM + co];
        a0.x += r0.x; a0.y += r0.y;
        a1.x += r1.x; a1.y += r1.y;
        a2.x += r2.x; a2.y += r2.y;
        a3.x += r3.x; a3.y += r3.y;
    }
    for (; i < end; ++i) {
        const float2 r = *(const float2*)&x[srcs[i] * DIM + co];
        a0.x += r.x; a0.y += r.y;
    }
    float2 s;
    s.x = (a0.x + a1.x) + (a2.x + a3.x);
    s.y = (a0.y + a1.y) + (a2.y + a3.y);
    *(float2*)&XAGG[n * DIM + co] = s;
}

// ---------------------------------------------------------------------------
// K6: z = relu(XAGG@W_in + x@W_self + b)  (in place over XAGG)
//     + per-graph sums via run-compressed atomics (batch_ids sorted)
// ---------------------------------------------------------------------------
__global__ __launch_bounds__(256) void gemm_z(
    const float* __restrict__ XAGG_in, const float* __restrict__ x,
    const float* __restrict__ W_in, const float* __restrict__ W_self,
    const float* __restrict__ b, const int* __restrict__ bid,
    float* __restrict__ Z, float* __restrict__ gsum)
{
    __shared__ float sa[16 * DIM];
    __shared__ float sb[16 * DIM];
    __shared__ int sbid[16];
    const int base = blockIdx.x * 16;
    const int t = threadIdx.x;
    {
        const float4* ga = (const float4*)(XAGG_in + base * DIM);
        const float4* gb = (const float4*)(x + base * DIM);
        float4* la = (float4*)sa;
        float4* lb = (float4*)sb;
        for (int i = t; i < 16 * DIM / 4; i += 256) { la[i] = ga[i]; lb[i] = gb[i]; }
        if (t < 16) sbid[t] = bid[base + t];
    }
    __syncthreads();

    const int half = t >> 7, c = t & 127;
    const float* __restrict__ W = half ? W_self : W_in;
    const float4* A4 = (const float4*)(half ? sb : sa);

    float acc[16];
#pragma unroll
    for (int r = 0; r < 16; ++r) acc[r] = 0.f;

    for (int k4 = 0; k4 < DIM / 4; ++k4) {
        const float w0 = W[(k4 * 4 + 0) * DIM + c];
        const float w1 = W[(k4 * 4 + 1) * DIM + c];
        const float w2 = W[(k4 * 4 + 2) * DIM + c];
        const float w3 = W[(k4 * 4 + 3) * DIM + c];
#pragma unroll
        for (int r = 0; r < 16; ++r) {
            const float4 xv = A4[r * (DIM / 4) + k4];
            acc[r] = fmaf(xv.x, w0, acc[r]);
            acc[r] = fmaf(xv.y, w1, acc[r]);
            acc[r] = fmaf(xv.z, w2, acc[r]);
            acc[r] = fmaf(xv.w, w3, acc[r]);
        }
    }
    __syncthreads();
    if (half) {
#pragma unroll
        for (int r = 0; r < 16; ++r) sa[r * DIM + c] = acc[r];
    }
    __syncthreads();
    if (!half) {
        const float bv = b[c];
        float run = 0.f;
        int cur = sbid[0];
#pragma unroll
        for (int r = 0; r < 16; ++r) {
            const float z = fmaxf(acc[r] + sa[r * DIM + c] + bv, 0.f);
            Z[(base + r) * DIM + c] = z;
            const int g = sbid[r];
            if (g != cur) { unsafeAtomicAdd(&gsum[cur * DIM + c], run); run = 0.f; cur = g; }
            run += z;
        }
        unsafeAtomicAdd(&gsum[cur * DIM + c], run);
    }
}

// ---------------------------------------------------------------------------
// K7: U12 = z @ [W_e1_top | W_e1_bot] (+b_e1 on U1 half), bf16 interleaved
// ---------------------------------------------------------------------------
__global__ __launch_bounds__(256) void gemm_u12(
    const float* __restrict__ Z,
    const float* __restrict__ W_e1, const float* __restrict__ b_e1,
    ushort* __restrict__ U12)
{
    __shared__ float xs[16 * DIM];
    const int base = blockIdx.x * 16;
    const int t = threadIdx.x;
    {
        const float4* g = (const float4*)(Z + base * DIM);
        float4* l = (float4*)xs;
        for (int i = t; i < 16 * DIM / 4; i += 256) l[i] = g[i];
    }
    __syncthreads();

    const int half = t >> 7, c = t & 127;
    const float* __restrict__ W = W_e1 + half * 128 * DIM;
    const float4* A4 = (const float4*)xs;

    float acc[16];
#pragma unroll
    for (int r = 0; r < 16; ++r) acc[r] = 0.f;

    for (int k4 = 0; k4 < DIM / 4; ++k4) {
        const float w0 = W[(k4 * 4 + 0) * DIM + c];
        const float w1 = W[(k4 * 4 + 1) * DIM + c];
        const float w2 = W[(k4 * 4 + 2) * DIM + c];
        const float w3 = W[(k4 * 4 + 3) * DIM + c];
#pragma unroll
        for (int r = 0; r < 16; ++r) {
            const float4 xv = A4[r * (DIM / 4) + k4];
            acc[r] = fmaf(xv.x, w0, acc[r]);
            acc[r] = fmaf(xv.y, w1, acc[r]);
            acc[r] = fmaf(xv.z, w2, acc[r]);
            acc[r] = fmaf(xv.w, w3, acc[r]);
        }
    }
    const float bv = half ? 0.f : b_e1[c];
    for (int r = 0; r < 16; ++r)
        U12[(base + r) * 256 + half * 128 + c] = f2bf(acc[r] + bv);
}

// ---------------------------------------------------------------------------
// K8: 16 lanes per edge, coalesced row reads + shfl reduce within group.
// ---------------------------------------------------------------------------
__device__ __forceinline__ void ch2(uint a, uint b, float wl, float wh,
                                    float& accl, float& acch)
{
    const float fl = fmaxf(__uint_as_float(a << 16) + __uint_as_float(b << 16), 0.f);
    const float fh = fmaxf(__uint_as_float(a & 0xffff0000u) + __uint_as_float(b & 0xffff0000u), 0.f);
    accl = fmaf(fl, wl, accl);
    acch = fmaf(fh, wh, acch);
}

__global__ __launch_bounds__(256) void edge_mlp3(
    const ushort* __restrict__ U12,
    const int* __restrict__ src, const int* __restrict__ dst,
    const float* __restrict__ W_e2, const float* __restrict__ b_e2,
    float* __restrict__ out)
{
    __shared__ float ws[DIM];
    const int t = threadIdx.x;
    if (t < DIM) ws[t] = W_e2[t];
    __syncthreads();

    const int l16  = t & 15;
    const int grp  = t >> 4;
    const int e    = blockIdx.x * 16 + grp;        // grid = 40000

    const int s = src[e];
    const int d = dst[e];

    const uint4 a  = *(const uint4*)(U12 + s * 256 + l16 * 8);
    const uint4 bv = *(const uint4*)(U12 + d * 256 + 128 + l16 * 8);
    const float4 w0 = ((const float4*)ws)[l16 * 2 + 0];
    const float4 w1 = ((const float4*)ws)[l16 * 2 + 1];

    float acc0 = 0.f, acc1 = 0.f;
    ch2(a.x, bv.x, w0.x, w0.y, acc0, acc1);
    ch2(a.y, bv.y, w0.z, w0.w, acc0, acc1);
    ch2(a.z, bv.z, w1.x, w1.y, acc0, acc1);
    ch2(a.w, bv.w, w1.z, w1.w, acc0, acc1);

    float p = acc0 + acc1;
#pragma unroll
    for (int off = 8; off >= 1; off >>= 1)
        p += __shfl_xor(p, off);

    if (l16 == 0) out[e] = p + b_e2[0];
}

// ---------------------------------------------------------------------------
// K9: classifier
// ---------------------------------------------------------------------------
__global__ __launch_bounds__(256) void classify(
    const float* __restrict__ gsum, const float* __restrict__ gcnt,
    const float* __restrict__ W_cls, const float* __restrict__ b_cls,
    float* __restrict__ out)
{
    const int t = threadIdx.x;
    if (t >= N_GRAPHS * N_CLASSES) return;
    const int g = t / N_CLASSES;
    const int c = t % N_CLASSES;
    const float inv = 1.0f / fmaxf(gcnt[g], 1.0f);
    float acc = 0.f;
    for (int k = 0; k < DIM; ++k)
        acc += gsum[g * DIM + k] * W_cls[k * N_CLASSES + c];
    out[g * N_CLASSES + c] = acc * inv + b_cls[c];
}

// ---------------------------------------------------------------------------
extern "C" void kernel_launch(void* const* d_in, const int* in_sizes, int n_in,
                              void* d_out, int out_size, void* d_ws, size_t ws_size,
                              hipStream_t stream)
{
    const float* x      = (const float*)d_in[0];
    const int*   eidx   = (const int*)  d_in[1];
    const int*   bid    = (const int*)  d_in[2];
    const float* W_in   = (const float*)d_in[3];
    const float* W_self = (const float*)d_in[4];
    const float* b      = (const float*)d_in[5];
    const float* W_e1   = (const float*)d_in[6];
    const float* b_e1   = (const float*)d_in[7];
    const float* W_e2   = (const float*)d_in[8];
    const float* b_e2   = (const float*)d_in[9];
    const float* W_cls  = (const float*)d_in[10];
    const float* b_cls  = (const float*)d_in[11];
    float* out = (float*)d_out;

    char* ws = (char*)d_ws;
    int*    cnt    = (int*)   (ws);                        // 40000 B
    float*  gsum   = (float*) (ws + 40960);                // 8192 B
    float*  gcnt   = (float*) (ws + 49152);                // 64 B
    int*    cursor = (int*)   (ws + 65536);                // 40000 B
    uint*   srcs   = (uint*)  (ws + 131072);               // 2,560,000 B
    float*  XAGG   = (float*) (ws + 131072 + 2560000);     // 5,120,000 B (becomes z)
    ushort* U12    = (ushort*)(ws + 131072 + 7680000);     // 5,120,000 B

    const int* src = eidx;
    const int* dst = eidx + N_EDGES;

    hipMemsetAsync(d_ws, 0, 65536, stream);   // cnt + gsum + gcnt

    hist_dst   <<<N_EDGES / 1024, 256, 0, stream>>>(dst, cnt);
    count_nodes<<<1, 256, 0, stream>>>(bid, gcnt);
    scan_k     <<<1, 1024, 0, stream>>>(cnt, cursor);
    fill_csr   <<<N_EDGES / 1024, 256, 0, stream>>>(src, dst, cursor, srcs);
    gather_x   <<<N_NODES / 4, 256, 0, stream>>>(x, cnt, cursor, srcs, XAGG);
    gemm_z     <<<N_NODES / 16, 256, 0, stream>>>(XAGG, x, W_in, W_self, b, bid, XAGG, gsum);
    gemm_u12   <<<N_NODES / 16, 256, 0, stream>>>(XAGG, W_e1, b_e1, U12);
    edge_mlp3  <<<N_EDGES / 16, 256, 0, stream>>>(U12, src, dst, W_e2, b_e2, out);
    classify   <<<1, 256, 0, stream>>>(gsum, gcnt, W_cls, b_cls, out + N_EDGES);
}

// Round 15
// 280.876 us; speedup vs baseline: 2.3234x; 1.0447x over previous
//
#include <hip/hip_runtime.h>

#define N_NODES   10000
#define N_EDGES   640000
#define DIM       128
#define N_GRAPHS  16
#define N_CLASSES 10

typedef unsigned int uint;
typedef unsigned short ushort;

__device__ __forceinline__ float bf2f(uint lo16) {
    return __uint_as_float(lo16 << 16);
}
__device__ __forceinline__ ushort f2bf(float f) {
    uint u = __float_as_uint(f);
    u += 0x7fffu + ((u >> 16) & 1u);      // round-to-nearest-even
    return (ushort)(u >> 16);
}

// ---------------------------------------------------------------------------
// K0: x (fp32) -> xb (bf16, 2.56 MB: fits per-XCD L2). uint = 2 channels.
// ---------------------------------------------------------------------------
__global__ __launch_bounds__(256) void conv_bf16(
    const float* __restrict__ x, uint* __restrict__ xb)
{
    const int idx = blockIdx.x * 256 + threadIdx.x;     // 1250 blocks exact
    const float4 v = ((const float4*)x)[idx];
    uint lo = (uint)f2bf(v.x) | ((uint)f2bf(v.y) << 16);
    uint hi = (uint)f2bf(v.z) | ((uint)f2bf(v.w) << 16);
    ((uint2*)xb)[idx] = make_uint2(lo, hi);
}

// ---------------------------------------------------------------------------
// K1: histogram of dst — 4 edges/thread
// ---------------------------------------------------------------------------
__global__ __launch_bounds__(256) void hist_dst(
    const int* __restrict__ dst, int* __restrict__ cnt)
{
    const int base = (blockIdx.x * 256 + threadIdx.x) * 4;   // 625 blocks exact
    const int d0 = dst[base + 0];
    const int d1 = dst[base + 1];
    const int d2 = dst[base + 2];
    const int d3 = dst[base + 3];
    atomicAdd(&cnt[d0], 1);
    atomicAdd(&cnt[d1], 1);
    atomicAdd(&cnt[d2], 1);
    atomicAdd(&cnt[d3], 1);
}

// ---------------------------------------------------------------------------
// K2: per-graph node counts (batch_ids) -> gcnt (float)
// ---------------------------------------------------------------------------
__global__ __launch_bounds__(256) void count_nodes(
    const int* __restrict__ bid, float* __restrict__ gcnt)
{
    __shared__ int h[N_GRAPHS];
    const int t = threadIdx.x;
    if (t < N_GRAPHS) h[t] = 0;
    __syncthreads();
    for (int n = t; n < N_NODES; n += 256) atomicAdd(&h[bid[n]], 1);
    __syncthreads();
    if (t < N_GRAPHS) gcnt[t] = (float)h[t];
}

// ---------------------------------------------------------------------------
// K3: exclusive prefix sum of cnt[10000] -> cursor (single block)
// ---------------------------------------------------------------------------
__global__ __launch_bounds__(1024) void scan_k(
    const int* __restrict__ cnt, int* __restrict__ cursor)
{
    __shared__ int s[1024];
    const int t = threadIdx.x;
    int local[10];
    int sum = 0;
    if (t < 1000) {
        for (int j = 0; j < 10; ++j) { local[j] = sum; sum += cnt[t * 10 + j]; }
    }
    s[t] = (t < 1000) ? sum : 0;
    __syncthreads();
    for (int st = 1; st < 1024; st <<= 1) {
        int v = (t >= st) ? s[t - st] : 0;
        __syncthreads();
        s[t] += v;
        __syncthreads();
    }
    if (t < 1000) {
        const int off = (t == 0) ? 0 : s[t - 1];
        for (int j = 0; j < 10; ++j) cursor[t * 10 + j] = off + local[j];
    }
}

// ---------------------------------------------------------------------------
// K4: fill CSR — 4 edges/thread
// ---------------------------------------------------------------------------
__global__ __launch_bounds__(256) void fill_csr(
    const int* __restrict__ src, const int* __restrict__ dst,
    int* __restrict__ cursor, uint* __restrict__ srcs)
{
    const int base = (blockIdx.x * 256 + threadIdx.x) * 4;   // 625 blocks exact
    const int d0 = dst[base + 0];
    const int d1 = dst[base + 1];
    const int d2 = dst[base + 2];
    const int d3 = dst[base + 3];
    const int s0 = src[base + 0];
    const int s1 = src[base + 1];
    const int s2 = src[base + 2];
    const int s3 = src[base + 3];
    const int p0 = atomicAdd(&cursor[d0], 1);
    const int p1 = atomicAdd(&cursor[d1], 1);
    const int p2 = atomicAdd(&cursor[d2], 1);
    const int p3 = atomicAdd(&cursor[d3], 1);
    srcs[p0] = (uint)s0;
    srcs[p1] = (uint)s1;
    srcs[p2] = (uint)s2;
    srcs[p3] = (uint)s3;
}

// ---------------------------------------------------------------------------
// K5: XAGG[n] = sum over in-edges of xb[src] (bf16 rows, L2-resident).
// Wave per node; lane reads 1 uint (2 channels) -> 256B/row per wave-instr.
// ---------------------------------------------------------------------------
__global__ __launch_bounds__(256) void gather_xb(
    const uint* __restrict__ xb,
    const int* __restrict__ cnt, const int* __restrict__ cursor,
    const uint* __restrict__ srcs,
    float* __restrict__ XAGG)
{
    const int n    = blockIdx.x * 4 + (threadIdx.x >> 6);
    const int lane = threadIdx.x & 63;
    const int end  = cursor[n];
    int i = end - cnt[n];

    float a0 = 0.f, b0 = 0.f, a1 = 0.f, b1 = 0.f;
    float a2 = 0.f, b2 = 0.f, a3 = 0.f, b3 = 0.f;

    for (; i + 4 <= end; i += 4) {
        const uint s0 = srcs[i], s1 = srcs[i + 1], s2 = srcs[i + 2], s3 = srcs[i + 3];
        const uint v0 = xb[s0 * 64 + lane];
        const uint v1 = xb[s1 * 64 + lane];
        const uint v2 = xb[s2 * 64 + lane];
        const uint v3 = xb[s3 * 64 + lane];
        a0 += bf2f(v0 & 0xffffu); b0 += bf2f(v0 >> 16);
        a1 += bf2f(v1 & 0xffffu); b1 += bf2f(v1 >> 16);
        a2 += bf2f(v2 & 0xffffu); b2 += bf2f(v2 >> 16);
        a3 += bf2f(v3 & 0xffffu); b3 += bf2f(v3 >> 16);
    }
    for (; i < end; ++i) {
        const uint v = xb[srcs[i] * 64 + lane];
        a0 += bf2f(v & 0xffffu); b0 += bf2f(v >> 16);
    }
    float2 s;
    s.x = (a0 + a1) + (a2 + a3);
    s.y = (b0 + b1) + (b2 + b3);
    *(float2*)&XAGG[n * DIM + lane * 2] = s;
}

// ---------------------------------------------------------------------------
// K6: fused: z = relu(XAGG@W_in + x@W_self + b) (LDS only, never stored)
//     + per-graph sums (run-compressed atomics, batch_ids sorted)
//     + U12 = z @ [W_e1_top | W_e1_bot] (+b_e1), bf16 interleaved
// ---------------------------------------------------------------------------
__global__ __launch_bounds__(256) void gemm_zu(
    const float* __restrict__ XAGG_in, const float* __restrict__ x,
    const float* __restrict__ W_in, const float* __restrict__ W_self,
    const float* __restrict__ b, const int* __restrict__ bid,
    const float* __restrict__ W_e1, const float* __restrict__ b_e1,
    float* __restrict__ gsum, ushort* __restrict__ U12)
{
    __shared__ float sa[16 * DIM];
    __shared__ float sb[16 * DIM];
    __shared__ int sbid[16];
    const int base = blockIdx.x * 16;
    const int t = threadIdx.x;
    {
        const float4* ga = (const float4*)(XAGG_in + base * DIM);
        const float4* gb = (const float4*)(x + base * DIM);
        float4* la = (float4*)sa;
        float4* lb = (float4*)sb;
        for (int i = t; i < 16 * DIM / 4; i += 256) { la[i] = ga[i]; lb[i] = gb[i]; }
        if (t < 16) sbid[t] = bid[base + t];
    }
    __syncthreads();

    const int half = t >> 7, c = t & 127;

    // --- matmul 1: half0 = XAGG@W_in, half1 = x@W_self ---
    {
        const float* __restrict__ W = half ? W_self : W_in;
        const float4* A4 = (const float4*)(half ? sb : sa);
        float acc[16];
#pragma unroll
        for (int r = 0; r < 16; ++r) acc[r] = 0.f;
        for (int k4 = 0; k4 < DIM / 4; ++k4) {
            const float w0 = W[(k4 * 4 + 0) * DIM + c];
            const float w1 = W[(k4 * 4 + 1) * DIM + c];
            const float w2 = W[(k4 * 4 + 2) * DIM + c];
            const float w3 = W[(k4 * 4 + 3) * DIM + c];
#pragma unroll
            for (int r = 0; r < 16; ++r) {
                const float4 xv = A4[r * (DIM / 4) + k4];
                acc[r] = fmaf(xv.x, w0, acc[r]);
                acc[r] = fmaf(xv.y, w1, acc[r]);
                acc[r] = fmaf(xv.z, w2, acc[r]);
                acc[r] = fmaf(xv.w, w3, acc[r]);
            }
        }
        __syncthreads();
        if (half) {
#pragma unroll
            for (int r = 0; r < 16; ++r) sb[r * DIM + c] = acc[r];
        }
        __syncthreads();
        if (!half) {
            const float bv = b[c];
            float run = 0.f;
            int cur = sbid[0];
#pragma unroll
            for (int r = 0; r < 16; ++r) {
                const float z = fmaxf(acc[r] + sb[r * DIM + c] + bv, 0.f);
                sa[r * DIM + c] = z;                    // z lives in LDS only
                const int g = sbid[r];
                if (g != cur) { unsafeAtomicAdd(&gsum[cur * DIM + c], run); run = 0.f; cur = g; }
                run += z;
            }
            unsafeAtomicAdd(&gsum[cur * DIM + c], run);
        }
        __syncthreads();
    }

    // --- matmul 2: U12 = z @ [W_e1_top | W_e1_bot] ---
    {
        const float* __restrict__ W = W_e1 + half * 128 * DIM;
        const float4* Z4 = (const float4*)sa;
        float acc[16];
#pragma unroll
        for (int r = 0; r < 16; ++r) acc[r] = 0.f;
        for (int k4 = 0; k4 < DIM / 4; ++k4) {
            const float w0 = W[(k4 * 4 + 0) * DIM + c];
            const float w1 = W[(k4 * 4 + 1) * DIM + c];
            const float w2 = W[(k4 * 4 + 2) * DIM + c];
            const float w3 = W[(k4 * 4 + 3) * DIM + c];
#pragma unroll
            for (int r = 0; r < 16; ++r) {
                const float4 xv = Z4[r * (DIM / 4) + k4];
                acc[r] = fmaf(xv.x, w0, acc[r]);
                acc[r] = fmaf(xv.y, w1, acc[r]);
                acc[r] = fmaf(xv.z, w2, acc[r]);
                acc[r] = fmaf(xv.w, w3, acc[r]);
            }
        }
        const float bv = half ? 0.f : b_e1[c];
        for (int r = 0; r < 16; ++r)
            U12[(base + r) * 256 + half * 128 + c] = f2bf(acc[r] + bv);
    }
}

// ---------------------------------------------------------------------------
// K8: 16 lanes per edge, coalesced row reads + shfl reduce within group.
// ---------------------------------------------------------------------------
__device__ __forceinline__ void ch2(uint a, uint b, float wl, float wh,
                                    float& accl, float& acch)
{
    const float fl = fmaxf(__uint_as_float(a << 16) + __uint_as_float(b << 16), 0.f);
    const float fh = fmaxf(__uint_as_float(a & 0xffff0000u) + __uint_as_float(b & 0xffff0000u), 0.f);
    accl = fmaf(fl, wl, accl);
    acch = fmaf(fh, wh, acch);
}

__global__ __launch_bounds__(256) void edge_mlp3(
    const ushort* __restrict__ U12,
    const int* __restrict__ src, const int* __restrict__ dst,
    const float* __restrict__ W_e2, const float* __restrict__ b_e2,
    float* __restrict__ out)
{
    __shared__ float ws[DIM];
    const int t = threadIdx.x;
    if (t < DIM) ws[t] = W_e2[t];
    __syncthreads();

    const int l16  = t & 15;
    const int grp  = t >> 4;
    const int e    = blockIdx.x * 16 + grp;        // grid = 40000

    const int s = src[e];
    const int d = dst[e];

    const uint4 a  = *(const uint4*)(U12 + s * 256 + l16 * 8);
    const uint4 bv = *(const uint4*)(U12 + d * 256 + 128 + l16 * 8);
    const float4 w0 = ((const float4*)ws)[l16 * 2 + 0];
    const float4 w1 = ((const float4*)ws)[l16 * 2 + 1];

    float acc0 = 0.f, acc1 = 0.f;
    ch2(a.x, bv.x, w0.x, w0.y, acc0, acc1);
    ch2(a.y, bv.y, w0.z, w0.w, acc0, acc1);
    ch2(a.z, bv.z, w1.x, w1.y, acc0, acc1);
    ch2(a.w, bv.w, w1.z, w1.w, acc0, acc1);

    float p = acc0 + acc1;
#pragma unroll
    for (int off = 8; off >= 1; off >>= 1)
        p += __shfl_xor(p, off);

    if (l16 == 0) out[e] = p + b_e2[0];
}

// ---------------------------------------------------------------------------
// K9: classifier
// ---------------------------------------------------------------------------
__global__ __launch_bounds__(256) void classify(
    const float* __restrict__ gsum, const float* __restrict__ gcnt,
    const float* __restrict__ W_cls, const float* __restrict__ b_cls,
    float* __restrict__ out)
{
    const int t = threadIdx.x;
    if (t >= N_GRAPHS * N_CLASSES) return;
    const int g = t / N_CLASSES;
    const int c = t % N_CLASSES;
    const float inv = 1.0f / fmaxf(gcnt[g], 1.0f);
    float acc = 0.f;
    for (int k = 0; k < DIM; ++k)
        acc += gsum[g * DIM + k] * W_cls[k * N_CLASSES + c];
    out[g * N_CLASSES + c] = acc * inv + b_cls[c];
}

// ---------------------------------------------------------------------------
extern "C" void kernel_launch(void* const* d_in, const int* in_sizes, int n_in,
                              void* d_out, int out_size, void* d_ws, size_t ws_size,
                              hipStream_t stream)
{
    const float* x      = (const float*)d_in[0];
    const int*   eidx   = (const int*)  d_in[1];
    const int*   bid    = (const int*)  d_in[2];
    const float* W_in   = (const float*)d_in[3];
    const float* W_self = (const float*)d_in[4];
    const float* b      = (const float*)d_in[5];
    const float* W_e1   = (const float*)d_in[6];
    const float* b_e1   = (const float*)d_in[7];
    const float* W_e2   = (const float*)d_in[8];
    const float* b_e2   = (const float*)d_in[9];
    const float* W_cls  = (const float*)d_in[10];
    const float* b_cls  = (const float*)d_in[11];
    float* out = (float*)d_out;

    char* ws = (char*)d_ws;
    int*    cnt    = (int*)   (ws);                         // 40000 B
    float*  gsum   = (float*) (ws + 40960);                 // 8192 B
    float*  gcnt   = (float*) (ws + 49152);                 // 64 B
    int*    cursor = (int*)   (ws + 65536);                 // 40000 B
    uint*   srcs   = (uint*)  (ws + 131072);                // 2,560,000 B
    float*  XAGG   = (float*) (ws + 131072 + 2560000);      // 5,120,000 B
    ushort* U12    = (ushort*)(ws + 131072 + 7680000);      // 5,120,000 B
    uint*   xb     = (uint*)  (ws + 131072 + 12800000);     // 2,560,000 B

    const int* src = eidx;
    const int* dst = eidx + N_EDGES;

    hipMemsetAsync(d_ws, 0, 65536, stream);   // cnt + gsum + gcnt

    conv_bf16  <<<(N_NODES * DIM / 4) / 256, 256, 0, stream>>>(x, xb);
    hist_dst   <<<N_EDGES / 1024, 256, 0, stream>>>(dst, cnt);
    count_nodes<<<1, 256, 0, stream>>>(bid, gcnt);
    scan_k     <<<1, 1024, 0, stream>>>(cnt, cursor);
    fill_csr   <<<N_EDGES / 1024, 256, 0, stream>>>(src, dst, cursor, srcs);
    gather_xb  <<<N_NODES / 4, 256, 0, stream>>>(xb, cnt, cursor, srcs, XAGG);
    gemm_zu    <<<N_NODES / 16, 256, 0, stream>>>(XAGG, x, W_in, W_self, b, bid,
                                                  W_e1, b_e1, gsum, U12);
    edge_mlp3  <<<N_EDGES / 16, 256, 0, stream>>>(U12, src, dst, W_e2, b_e2, out);
    classify   <<<1, 256, 0, stream>>>(gsum, gcnt, W_cls, b_cls, out + N_EDGES);
}